// Round 1
// baseline (6509.684 us; speedup 1.0000x reference)
//
#include <hip/hip_runtime.h>
#include <hip/hip_bf16.h>

#define F 256            // feature dim == filters
#define GEMM_ROWS 16

// C[row0..row0+15][0..255] = X[rows] @ W  (X: N x 256 row-major, W: 256 x 256 row-major)
__global__ __launch_bounds__(256) void gemm_xw(const float* __restrict__ X,
                                               const float* __restrict__ W,
                                               float* __restrict__ Out) {
    __shared__ float xs[GEMM_ROWS * F];
    const int tid = threadIdx.x;
    const int row0 = blockIdx.x * GEMM_ROWS;

    // stage 16 rows of X (N = 10000 = 625*16, exact — no guards needed)
#pragma unroll
    for (int r = 0; r < GEMM_ROWS; ++r)
        xs[r * F + tid] = X[(size_t)(row0 + r) * F + tid];
    __syncthreads();

    float acc[GEMM_ROWS];
#pragma unroll
    for (int r = 0; r < GEMM_ROWS; ++r) acc[r] = 0.f;

    const float4* xs4 = (const float4*)xs;
    for (int kk = 0; kk < F; kk += 4) {
        const float w0 = W[(size_t)(kk + 0) * F + tid];
        const float w1 = W[(size_t)(kk + 1) * F + tid];
        const float w2 = W[(size_t)(kk + 2) * F + tid];
        const float w3 = W[(size_t)(kk + 3) * F + tid];
#pragma unroll
        for (int r = 0; r < GEMM_ROWS; ++r) {
            const float4 xv = xs4[r * (F / 4) + (kk >> 2)];
            acc[r] = fmaf(xv.x, w0, acc[r]);
            acc[r] = fmaf(xv.y, w1, acc[r]);
            acc[r] = fmaf(xv.z, w2, acc[r]);
            acc[r] = fmaf(xv.w, w3, acc[r]);
        }
    }

#pragma unroll
    for (int r = 0; r < GEMM_ROWS; ++r)
        Out[(size_t)(row0 + r) * F + tid] = acc[r];
}

// out[dst[e]] += vals[e] * h[src[e]]   — one wave per edge, lane = 4 features
__global__ __launch_bounds__(256) void spmm_atomic(const float* __restrict__ h,
                                                   const float* __restrict__ vals,
                                                   const int* __restrict__ src,
                                                   const int* __restrict__ dst,
                                                   float* __restrict__ out,
                                                   int E) {
    const int wave = (blockIdx.x * blockDim.x + threadIdx.x) >> 6;
    const int lane = threadIdx.x & 63;
    if (wave >= E) return;

    const int   s = src[wave];
    const int   d = dst[wave];
    const float v = vals[wave];

    const float4 hv = ((const float4*)(h + (size_t)s * F))[lane];
    float* op = out + (size_t)d * F + lane * 4;
    atomicAdd(op + 0, hv.x * v);
    atomicAdd(op + 1, hv.y * v);
    atomicAdd(op + 2, hv.z * v);
    atomicAdd(op + 3, hv.w * v);
}

// out = relu(out / 3), in place, float4
__global__ __launch_bounds__(256) void finalize_kernel(float* __restrict__ out, int n4) {
    const int i = blockIdx.x * blockDim.x + threadIdx.x;
    if (i >= n4) return;
    float4 v = ((float4*)out)[i];
    const float s = 1.0f / 3.0f;
    v.x = fmaxf(v.x * s, 0.f);
    v.y = fmaxf(v.y * s, 0.f);
    v.z = fmaxf(v.z * s, 0.f);
    v.w = fmaxf(v.w * s, 0.f);
    ((float4*)out)[i] = v;
}

extern "C" void kernel_launch(void* const* d_in, const int* in_sizes, int n_in,
                              void* d_out, int out_size, void* d_ws, size_t ws_size,
                              hipStream_t stream) {
    const float* x     = (const float*)d_in[0];
    const float* Avals = (const float*)d_in[1];
    const float* W1    = (const float*)d_in[2];
    const float* W2    = (const float*)d_in[3];
    const float* W3    = (const float*)d_in[4];
    const int*   esrc  = (const int*)d_in[5];
    const int*   edst  = (const int*)d_in[6];
    float*       out   = (float*)d_out;

    const int N = in_sizes[0] / F;     // 10000
    const int E = in_sizes[5];         // 320000

    const size_t mat_elems = (size_t)N * F;
    const size_t mat_bytes = mat_elems * sizeof(float);

    float* ws0 = (float*)d_ws;
    float* ws1 = ws0 + mat_elems;

    const int gemm_grid = (N + GEMM_ROWS - 1) / GEMM_ROWS;     // 625
    const int spmm_grid = (E + 3) / 4;                         // 4 edges/block (256 thr)
    const int n4 = (int)(mat_elems / 4);
    const int fin_grid = (n4 + 255) / 256;

    // accumulate f3 + f2 + f1 into out, then finalize
    hipMemsetAsync(out, 0, mat_bytes, stream);

    // ---- branch 3: f3 = A^3 (x W3) ----
    gemm_xw<<<gemm_grid, 256, 0, stream>>>(x, W3, ws0);                       // h3
    hipMemsetAsync(ws1, 0, mat_bytes, stream);
    spmm_atomic<<<spmm_grid, 256, 0, stream>>>(ws0, Avals, esrc, edst, ws1, E); // A h3
    hipMemsetAsync(ws0, 0, mat_bytes, stream);
    spmm_atomic<<<spmm_grid, 256, 0, stream>>>(ws1, Avals, esrc, edst, ws0, E); // A^2 h3
    spmm_atomic<<<spmm_grid, 256, 0, stream>>>(ws0, Avals, esrc, edst, out, E); // + f3

    // ---- branch 2: f2 = A^2 (x W2) ----
    gemm_xw<<<gemm_grid, 256, 0, stream>>>(x, W2, ws1);                       // h2
    hipMemsetAsync(ws0, 0, mat_bytes, stream);
    spmm_atomic<<<spmm_grid, 256, 0, stream>>>(ws1, Avals, esrc, edst, ws0, E); // A h2
    spmm_atomic<<<spmm_grid, 256, 0, stream>>>(ws0, Avals, esrc, edst, out, E); // + f2

    // ---- branch 1: f1 = A (x W1) ----
    gemm_xw<<<gemm_grid, 256, 0, stream>>>(x, W1, ws1);                       // h1
    spmm_atomic<<<spmm_grid, 256, 0, stream>>>(ws1, Avals, esrc, edst, out, E); // + f1

    finalize_kernel<<<fin_grid, 256, 0, stream>>>(out, n4);
}

// Round 2
// 355.392 us; speedup vs baseline: 18.3169x; 18.3169x over previous
//
#include <hip/hip_runtime.h>
#include <hip/hip_bf16.h>

#define F 256
#define NF4 (F / 4)        // 64 float4 per row
#define GEMM_ROWS 16

// ---------------- GEMM: Out = X @ W (+ T) ----------------
template <bool ADD>
__global__ __launch_bounds__(256) void gemm_xw(const float* __restrict__ X,
                                               const float* __restrict__ W,
                                               const float* __restrict__ T,
                                               float* __restrict__ Out) {
    __shared__ float xs[GEMM_ROWS * F];
    const int tid = threadIdx.x;
    const int row0 = blockIdx.x * GEMM_ROWS;

#pragma unroll
    for (int r = 0; r < GEMM_ROWS; ++r)
        xs[r * F + tid] = X[(size_t)(row0 + r) * F + tid];
    __syncthreads();

    float acc[GEMM_ROWS];
#pragma unroll
    for (int r = 0; r < GEMM_ROWS; ++r)
        acc[r] = ADD ? T[(size_t)(row0 + r) * F + tid] : 0.f;

    const float4* xs4 = (const float4*)xs;
    for (int kk = 0; kk < F; kk += 4) {
        const float w0 = W[(size_t)(kk + 0) * F + tid];
        const float w1 = W[(size_t)(kk + 1) * F + tid];
        const float w2 = W[(size_t)(kk + 2) * F + tid];
        const float w3 = W[(size_t)(kk + 3) * F + tid];
#pragma unroll
        for (int r = 0; r < GEMM_ROWS; ++r) {
            const float4 xv = xs4[r * NF4 + (kk >> 2)];
            acc[r] = fmaf(xv.x, w0, acc[r]);
            acc[r] = fmaf(xv.y, w1, acc[r]);
            acc[r] = fmaf(xv.z, w2, acc[r]);
            acc[r] = fmaf(xv.w, w3, acc[r]);
        }
    }

#pragma unroll
    for (int r = 0; r < GEMM_ROWS; ++r)
        Out[(size_t)(row0 + r) * F + tid] = acc[r];
}

// ---------------- CSR build ----------------
__global__ __launch_bounds__(256) void count_kernel(const int* __restrict__ dst,
                                                    int* __restrict__ counts, int E) {
    const int e = blockIdx.x * blockDim.x + threadIdx.x;
    if (e < E) atomicAdd(&counts[dst[e]], 1);
}

// single-block exclusive scan over n counts -> row_start[0..n]
__global__ __launch_bounds__(256) void scan_kernel(const int* __restrict__ counts,
                                                   int* __restrict__ row_start, int n) {
    __shared__ int buf[256];
    const int tid = threadIdx.x;
    int carry = 0;
    for (int base = 0; base < n; base += 256) {
        const int i = base + tid;
        const int v = (i < n) ? counts[i] : 0;
        buf[tid] = v;
        __syncthreads();
        for (int off = 1; off < 256; off <<= 1) {
            const int t = (tid >= off) ? buf[tid - off] : 0;
            __syncthreads();
            buf[tid] += t;
            __syncthreads();
        }
        if (i < n) row_start[i] = carry + buf[tid] - v;   // exclusive
        carry += buf[255];
        __syncthreads();
    }
    if (tid == 0) row_start[n] = carry;
}

__global__ __launch_bounds__(256) void init_cursor_kernel(const int* __restrict__ row_start,
                                                          int* __restrict__ cursor, int n) {
    const int i = blockIdx.x * blockDim.x + threadIdx.x;
    if (i < n) cursor[i] = row_start[i];
}

__global__ __launch_bounds__(256) void scatter_kernel(const int* __restrict__ src,
                                                      const int* __restrict__ dst,
                                                      const float* __restrict__ vals,
                                                      int* __restrict__ cursor,
                                                      int2* __restrict__ pack, int E) {
    const int e = blockIdx.x * blockDim.x + threadIdx.x;
    if (e < E) {
        const int pos = atomicAdd(&cursor[dst[e]], 1);
        pack[pos] = make_int2(src[e], __float_as_int(vals[e]));
    }
}

// ---------------- SPMM: out[r] = sum_{k in row r} v_k * h[src_k]  ----------------
// one wave per dst row; lane owns 4 features (float4). No atomics.
__global__ __launch_bounds__(256) void spmm_csr(const float4* __restrict__ h4,
                                                const int* __restrict__ row_start,
                                                const int2* __restrict__ pack,
                                                float4* __restrict__ out4,
                                                int N, int final_mode) {
    const int gid = blockIdx.x * blockDim.x + threadIdx.x;
    const int row = gid >> 6;
    const int lane = threadIdx.x & 63;
    if (row >= N) return;

    const int k0 = row_start[row];
    const int k1 = row_start[row + 1];

    float4 acc = make_float4(0.f, 0.f, 0.f, 0.f);
    for (int k = k0; k < k1; ++k) {
        const int2 p = pack[k];
        const float v = __int_as_float(p.y);
        const float4 hv = h4[(size_t)p.x * NF4 + lane];
        acc.x = fmaf(hv.x, v, acc.x);
        acc.y = fmaf(hv.y, v, acc.y);
        acc.z = fmaf(hv.z, v, acc.z);
        acc.w = fmaf(hv.w, v, acc.w);
    }

    if (final_mode) {
        const float s = 1.0f / 3.0f;
        acc.x = fmaxf(acc.x * s, 0.f);
        acc.y = fmaxf(acc.y * s, 0.f);
        acc.z = fmaxf(acc.z * s, 0.f);
        acc.w = fmaxf(acc.w * s, 0.f);
    }
    out4[(size_t)row * NF4 + lane] = acc;
}

extern "C" void kernel_launch(void* const* d_in, const int* in_sizes, int n_in,
                              void* d_out, int out_size, void* d_ws, size_t ws_size,
                              hipStream_t stream) {
    const float* x     = (const float*)d_in[0];
    const float* Avals = (const float*)d_in[1];
    const float* W1    = (const float*)d_in[2];
    const float* W2    = (const float*)d_in[3];
    const float* W3    = (const float*)d_in[4];
    const int*   esrc  = (const int*)d_in[5];
    const int*   edst  = (const int*)d_in[6];
    float*       out   = (float*)d_out;

    const int N = in_sizes[0] / F;   // 10000
    const int E = in_sizes[5];       // 320000

    const size_t mat_elems = (size_t)N * F;

    // workspace layout
    float* hbuf      = (float*)d_ws;                    // N*F floats
    int*   row_start = (int*)(hbuf + mat_elems);        // N+1
    int*   cursor    = row_start + (N + 1);             // N
    int*   counts    = cursor + N;                      // N
    int*   pad       = counts + N;                      // keep pack 8B-aligned
    int2*  pack      = (int2*)(((uintptr_t)pad + 7) & ~(uintptr_t)7);  // E int2

    const int eb = (E + 255) / 256;                 // 1250
    const int nb = (N + 255) / 256;                 // 40
    const int spmm_grid = (N * 64 + 255) / 256;     // 2500
    const int gemm_grid = N / GEMM_ROWS;            // 625

    // ---- build dst-CSR (rebuilt every call; order within a row is arbitrary) ----
    hipMemsetAsync(counts, 0, (size_t)N * sizeof(int), stream);
    count_kernel<<<eb, 256, 0, stream>>>(edst, counts, E);
    scan_kernel<<<1, 256, 0, stream>>>(counts, row_start, N);
    init_cursor_kernel<<<nb, 256, 0, stream>>>(row_start, cursor, N);
    scatter_kernel<<<eb, 256, 0, stream>>>(esrc, edst, Avals, cursor, pack, E);

    // ---- Horner: out = relu( A(h1 + A(h2 + A h3)) / 3 ) ----
    gemm_xw<false><<<gemm_grid, 256, 0, stream>>>(x, W3, nullptr, hbuf);            // h3
    spmm_csr<<<spmm_grid, 256, 0, stream>>>((const float4*)hbuf, row_start, pack,
                                            (float4*)out, N, 0);                    // t = A h3
    gemm_xw<true><<<gemm_grid, 256, 0, stream>>>(x, W2, out, hbuf);                 // h2 + t
    spmm_csr<<<spmm_grid, 256, 0, stream>>>((const float4*)hbuf, row_start, pack,
                                            (float4*)out, N, 0);                    // t = A(...)
    gemm_xw<true><<<gemm_grid, 256, 0, stream>>>(x, W1, out, hbuf);                 // h1 + t
    spmm_csr<<<spmm_grid, 256, 0, stream>>>((const float4*)hbuf, row_start, pack,
                                            (float4*)out, N, 1);                    // relu(/3)
}

// Round 3
// 243.484 us; speedup vs baseline: 26.7356x; 1.4596x over previous
//
#include <hip/hip_runtime.h>
#include <hip/hip_bf16.h>

#define F 256
#define NF4 (F / 4)
#define GEMM_ROWS 16

// ---------------- fused triple GEMM: H{1,2,3} = X @ W{1,2,3} ----------------
__global__ __launch_bounds__(256) void gemm3_xw(const float* __restrict__ X,
                                                const float* __restrict__ W1,
                                                const float* __restrict__ W2,
                                                const float* __restrict__ W3,
                                                float* __restrict__ H1,
                                                float* __restrict__ H2,
                                                float* __restrict__ H3) {
    __shared__ float xs[GEMM_ROWS * F];
    const int tid = threadIdx.x;
    const int row0 = blockIdx.x * GEMM_ROWS;

#pragma unroll
    for (int r = 0; r < GEMM_ROWS; ++r)
        xs[r * F + tid] = X[(size_t)(row0 + r) * F + tid];
    __syncthreads();

    float a1[GEMM_ROWS], a2[GEMM_ROWS], a3[GEMM_ROWS];
#pragma unroll
    for (int r = 0; r < GEMM_ROWS; ++r) { a1[r] = 0.f; a2[r] = 0.f; a3[r] = 0.f; }

    const float4* xs4 = (const float4*)xs;
    for (int kk = 0; kk < F; kk += 4) {
        float w1v[4], w2v[4], w3v[4];
#pragma unroll
        for (int j = 0; j < 4; ++j) {
            w1v[j] = W1[(size_t)(kk + j) * F + tid];
            w2v[j] = W2[(size_t)(kk + j) * F + tid];
            w3v[j] = W3[(size_t)(kk + j) * F + tid];
        }
#pragma unroll
        for (int r = 0; r < GEMM_ROWS; ++r) {
            const float4 xv = xs4[r * NF4 + (kk >> 2)];
            a1[r] = fmaf(xv.x, w1v[0], a1[r]); a1[r] = fmaf(xv.y, w1v[1], a1[r]);
            a1[r] = fmaf(xv.z, w1v[2], a1[r]); a1[r] = fmaf(xv.w, w1v[3], a1[r]);
            a2[r] = fmaf(xv.x, w2v[0], a2[r]); a2[r] = fmaf(xv.y, w2v[1], a2[r]);
            a2[r] = fmaf(xv.z, w2v[2], a2[r]); a2[r] = fmaf(xv.w, w2v[3], a2[r]);
            a3[r] = fmaf(xv.x, w3v[0], a3[r]); a3[r] = fmaf(xv.y, w3v[1], a3[r]);
            a3[r] = fmaf(xv.z, w3v[2], a3[r]); a3[r] = fmaf(xv.w, w3v[3], a3[r]);
        }
    }

#pragma unroll
    for (int r = 0; r < GEMM_ROWS; ++r) {
        H1[(size_t)(row0 + r) * F + tid] = a1[r];
        H2[(size_t)(row0 + r) * F + tid] = a2[r];
        H3[(size_t)(row0 + r) * F + tid] = a3[r];
    }
}

// ---------------- single GEMM (fallback path): Out = X @ W (+ T) ----------------
template <bool ADD>
__global__ __launch_bounds__(256) void gemm_xw(const float* __restrict__ X,
                                               const float* __restrict__ W,
                                               const float* __restrict__ T,
                                               float* __restrict__ Out) {
    __shared__ float xs[GEMM_ROWS * F];
    const int tid = threadIdx.x;
    const int row0 = blockIdx.x * GEMM_ROWS;

#pragma unroll
    for (int r = 0; r < GEMM_ROWS; ++r)
        xs[r * F + tid] = X[(size_t)(row0 + r) * F + tid];
    __syncthreads();

    float acc[GEMM_ROWS];
#pragma unroll
    for (int r = 0; r < GEMM_ROWS; ++r)
        acc[r] = ADD ? T[(size_t)(row0 + r) * F + tid] : 0.f;

    const float4* xs4 = (const float4*)xs;
    for (int kk = 0; kk < F; kk += 4) {
        const float w0 = W[(size_t)(kk + 0) * F + tid];
        const float w1 = W[(size_t)(kk + 1) * F + tid];
        const float w2 = W[(size_t)(kk + 2) * F + tid];
        const float w3 = W[(size_t)(kk + 3) * F + tid];
#pragma unroll
        for (int r = 0; r < GEMM_ROWS; ++r) {
            const float4 xv = xs4[r * NF4 + (kk >> 2)];
            acc[r] = fmaf(xv.x, w0, acc[r]);
            acc[r] = fmaf(xv.y, w1, acc[r]);
            acc[r] = fmaf(xv.z, w2, acc[r]);
            acc[r] = fmaf(xv.w, w3, acc[r]);
        }
    }

#pragma unroll
    for (int r = 0; r < GEMM_ROWS; ++r)
        Out[(size_t)(row0 + r) * F + tid] = acc[r];
}

// ---------------- CSR build ----------------
__global__ __launch_bounds__(256) void count_kernel(const int* __restrict__ dst,
                                                    int* __restrict__ counts, int E) {
    const int e = blockIdx.x * blockDim.x + threadIdx.x;
    if (e < E) atomicAdd(&counts[dst[e]], 1);
}

// per-block exclusive scan; block totals to partials
__global__ __launch_bounds__(256) void scan_block(const int* __restrict__ counts,
                                                  int* __restrict__ row_start,
                                                  int* __restrict__ partials, int n) {
    __shared__ int buf[256];
    const int tid = threadIdx.x;
    const int i = blockIdx.x * 256 + tid;
    const int v = (i < n) ? counts[i] : 0;
    buf[tid] = v;
    __syncthreads();
    for (int off = 1; off < 256; off <<= 1) {
        const int t = (tid >= off) ? buf[tid - off] : 0;
        __syncthreads();
        buf[tid] += t;
        __syncthreads();
    }
    if (i < n) row_start[i] = buf[tid] - v;       // block-local exclusive
    if (tid == 255) partials[blockIdx.x] = buf[255];
}

// single block: exclusive scan of nb (<=256) partials
__global__ __launch_bounds__(256) void scan_partials(int* __restrict__ partials, int nb) {
    __shared__ int buf[256];
    const int tid = threadIdx.x;
    const int v = (tid < nb) ? partials[tid] : 0;
    buf[tid] = v;
    __syncthreads();
    for (int off = 1; off < 256; off <<= 1) {
        const int t = (tid >= off) ? buf[tid - off] : 0;
        __syncthreads();
        buf[tid] += t;
        __syncthreads();
    }
    if (tid < nb) partials[tid] = buf[tid] - v;   // exclusive offsets
}

// row_start += partials[block]; cursor = row_start; row_start[n] = E
__global__ __launch_bounds__(256) void add_offsets(int* __restrict__ row_start,
                                                   const int* __restrict__ partials,
                                                   int* __restrict__ cursor, int n, int E) {
    const int i = blockIdx.x * blockDim.x + threadIdx.x;
    if (i < n) {
        const int v = row_start[i] + partials[i >> 8];
        row_start[i] = v;
        cursor[i] = v;
    }
    if (i == 0) row_start[n] = E;
}

__global__ __launch_bounds__(256) void scatter_kernel(const int* __restrict__ src,
                                                      const int* __restrict__ dst,
                                                      const float* __restrict__ vals,
                                                      int* __restrict__ cursor,
                                                      int2* __restrict__ pack, int E) {
    const int e = blockIdx.x * blockDim.x + threadIdx.x;
    if (e < E) {
        const int pos = atomicAdd(&cursor[dst[e]], 1);
        pack[pos] = make_int2(src[e], __float_as_int(vals[e]));
    }
}

// ---------------- SPMM: out[r] = (sum_k v_k * h[src_k]) + add[r]; optional relu(/3) ----
// one wave per dst row; lane owns 4 features. Unroll-4 for memory-level parallelism.
// NOTE: addv/out4 may alias (row-local read-before-write) — deliberately NOT restrict.
__global__ __launch_bounds__(256) void spmm_csr(const float4* __restrict__ h4,
                                                const int* __restrict__ row_start,
                                                const int2* __restrict__ pack,
                                                const float4* addv,
                                                float4* out4,
                                                int N, int final_mode) {
    const int gid = blockIdx.x * blockDim.x + threadIdx.x;
    const int row = gid >> 6;
    const int lane = threadIdx.x & 63;
    if (row >= N) return;

    const int k0 = row_start[row];
    const int k1 = row_start[row + 1];

    float4 acc = addv ? addv[(size_t)row * NF4 + lane]
                      : make_float4(0.f, 0.f, 0.f, 0.f);

    int k = k0;
    for (; k + 4 <= k1; k += 4) {
        const int2 p0 = pack[k + 0];
        const int2 p1 = pack[k + 1];
        const int2 p2 = pack[k + 2];
        const int2 p3 = pack[k + 3];
        const float4 h0 = h4[(size_t)p0.x * NF4 + lane];
        const float4 h1 = h4[(size_t)p1.x * NF4 + lane];
        const float4 h2 = h4[(size_t)p2.x * NF4 + lane];
        const float4 h3 = h4[(size_t)p3.x * NF4 + lane];
        const float v0 = __int_as_float(p0.y), v1 = __int_as_float(p1.y);
        const float v2 = __int_as_float(p2.y), v3 = __int_as_float(p3.y);
        acc.x = fmaf(h0.x, v0, acc.x); acc.y = fmaf(h0.y, v0, acc.y);
        acc.z = fmaf(h0.z, v0, acc.z); acc.w = fmaf(h0.w, v0, acc.w);
        acc.x = fmaf(h1.x, v1, acc.x); acc.y = fmaf(h1.y, v1, acc.y);
        acc.z = fmaf(h1.z, v1, acc.z); acc.w = fmaf(h1.w, v1, acc.w);
        acc.x = fmaf(h2.x, v2, acc.x); acc.y = fmaf(h2.y, v2, acc.y);
        acc.z = fmaf(h2.z, v2, acc.z); acc.w = fmaf(h2.w, v2, acc.w);
        acc.x = fmaf(h3.x, v3, acc.x); acc.y = fmaf(h3.y, v3, acc.y);
        acc.z = fmaf(h3.z, v3, acc.z); acc.w = fmaf(h3.w, v3, acc.w);
    }
    for (; k < k1; ++k) {
        const int2 p = pack[k];
        const float v = __int_as_float(p.y);
        const float4 hv = h4[(size_t)p.x * NF4 + lane];
        acc.x = fmaf(hv.x, v, acc.x); acc.y = fmaf(hv.y, v, acc.y);
        acc.z = fmaf(hv.z, v, acc.z); acc.w = fmaf(hv.w, v, acc.w);
    }

    if (final_mode) {
        const float s = 1.0f / 3.0f;
        acc.x = fmaxf(acc.x * s, 0.f);
        acc.y = fmaxf(acc.y * s, 0.f);
        acc.z = fmaxf(acc.z * s, 0.f);
        acc.w = fmaxf(acc.w * s, 0.f);
    }
    out4[(size_t)row * NF4 + lane] = acc;
}

extern "C" void kernel_launch(void* const* d_in, const int* in_sizes, int n_in,
                              void* d_out, int out_size, void* d_ws, size_t ws_size,
                              hipStream_t stream) {
    const float* x     = (const float*)d_in[0];
    const float* Avals = (const float*)d_in[1];
    const float* W1    = (const float*)d_in[2];
    const float* W2    = (const float*)d_in[3];
    const float* W3    = (const float*)d_in[4];
    const int*   esrc  = (const int*)d_in[5];
    const int*   edst  = (const int*)d_in[6];
    float*       out   = (float*)d_out;

    const int N = in_sizes[0] / F;   // 10000
    const int E = in_sizes[5];       // 320000

    const size_t mat_elems = (size_t)N * F;

    const int eb = (E + 255) / 256;
    const int nb = (N + 255) / 256;                 // scan blocks (40)
    const int spmm_grid = (N * 64 + 255) / 256;
    const int gemm_grid = (N + GEMM_ROWS - 1) / GEMM_ROWS;

    // fused-path workspace layout: h2buf, h3buf, ints, pack
    const size_t need_fused =
        2 * mat_elems * sizeof(float) +
        (size_t)(3 * N + 1 + nb + 16) * sizeof(int) + 16 + (size_t)E * 8;

    if (ws_size >= need_fused) {
        float* h2buf     = (float*)d_ws;
        float* h3buf     = h2buf + mat_elems;
        int*   row_start = (int*)(h3buf + mat_elems);
        int*   cursor    = row_start + (N + 1);
        int*   counts    = cursor + N;
        int*   partials  = counts + N;
        int2*  pack      = (int2*)(((uintptr_t)(partials + nb) + 7) & ~(uintptr_t)7);

        // CSR build
        hipMemsetAsync(counts, 0, (size_t)N * sizeof(int), stream);
        count_kernel<<<eb, 256, 0, stream>>>(edst, counts, E);
        scan_block<<<nb, 256, 0, stream>>>(counts, row_start, partials, N);
        scan_partials<<<1, 256, 0, stream>>>(partials, nb);
        add_offsets<<<nb, 256, 0, stream>>>(row_start, partials, cursor, N, E);
        scatter_kernel<<<eb, 256, 0, stream>>>(esrc, edst, Avals, cursor, pack, E);

        // h1 -> out, h2 -> h2buf, h3 -> h3buf
        gemm3_xw<<<gemm_grid, 256, 0, stream>>>(x, W1, W2, W3, out, h2buf, h3buf);

        // Horner with adds fused into SPMM epilogue:
        // t = A h3 + h2      (in-place into h2buf: row-local read-before-write)
        spmm_csr<<<spmm_grid, 256, 0, stream>>>((const float4*)h3buf, row_start, pack,
                                                (const float4*)h2buf, (float4*)h2buf, N, 0);
        // t = A t + h1       (h1 lives in out; write into h3buf, now dead)
        spmm_csr<<<spmm_grid, 256, 0, stream>>>((const float4*)h2buf, row_start, pack,
                                                (const float4*)out, (float4*)h3buf, N, 0);
        // out = relu(A t / 3)
        spmm_csr<<<spmm_grid, 256, 0, stream>>>((const float4*)h3buf, row_start, pack,
                                                nullptr, (float4*)out, N, 1);
    } else {
        // fallback: sequential schedule (R2 footprint ~13 MB)
        float* hbuf      = (float*)d_ws;
        int*   row_start = (int*)(hbuf + mat_elems);
        int*   cursor    = row_start + (N + 1);
        int*   counts    = cursor + N;
        int*   partials  = counts + N;
        int2*  pack      = (int2*)(((uintptr_t)(partials + nb) + 7) & ~(uintptr_t)7);

        hipMemsetAsync(counts, 0, (size_t)N * sizeof(int), stream);
        count_kernel<<<eb, 256, 0, stream>>>(edst, counts, E);
        scan_block<<<nb, 256, 0, stream>>>(counts, row_start, partials, N);
        scan_partials<<<1, 256, 0, stream>>>(partials, nb);
        add_offsets<<<nb, 256, 0, stream>>>(row_start, partials, cursor, N, E);
        scatter_kernel<<<eb, 256, 0, stream>>>(esrc, edst, Avals, cursor, pack, E);

        gemm_xw<false><<<gemm_grid, 256, 0, stream>>>(x, W3, nullptr, hbuf);
        spmm_csr<<<spmm_grid, 256, 0, stream>>>((const float4*)hbuf, row_start, pack,
                                                nullptr, (float4*)out, N, 0);
        gemm_xw<true><<<gemm_grid, 256, 0, stream>>>(x, W2, out, hbuf);
        spmm_csr<<<spmm_grid, 256, 0, stream>>>((const float4*)hbuf, row_start, pack,
                                                nullptr, (float4*)out, N, 0);
        gemm_xw<true><<<gemm_grid, 256, 0, stream>>>(x, W1, out, hbuf);
        spmm_csr<<<spmm_grid, 256, 0, stream>>>((const float4*)hbuf, row_start, pack,
                                                nullptr, (float4*)out, N, 1);
    }
}

// Round 4
// 201.082 us; speedup vs baseline: 32.3733x; 1.2109x over previous
//
#include <hip/hip_runtime.h>
#include <hip/hip_bf16.h>

#define F 256
#define NF4 (F / 4)
#define NF2 (F / 2)
#define GEMM_ROWS 16

typedef short v8s __attribute__((ext_vector_type(8)));
typedef float v4f __attribute__((ext_vector_type(4)));

__device__ __forceinline__ unsigned short f2bf_rtne(float f) {
    unsigned int u = __float_as_uint(f);
    u += 0x7FFFu + ((u >> 16) & 1u);
    return (unsigned short)(u >> 16);
}

// ============ bf16 MFMA path ============
// xpack layout: [mtile][ks 0..7][lane 0..63][j 0..7] bf16,
//   element = x[mtile*16 + (lane&15)][ks*32 + (lane>>4)*8 + j]
__global__ __launch_bounds__(256) void pack_x(const float* __restrict__ X,
                                              short* __restrict__ xpack, int MT) {
    const int t = blockIdx.x * 256 + threadIdx.x;
    if (t >= MT * 8 * 64) return;
    const int lane = t & 63;
    const int ks = (t >> 6) & 7;
    const int mtile = t >> 9;
    const int row = mtile * 16 + (lane & 15);
    const int kbase = ks * 32 + ((lane >> 4) << 3);
    const float* src = X + (size_t)row * F + kbase;
    v8s o;
#pragma unroll
    for (int j = 0; j < 8; ++j) o[j] = (short)f2bf_rtne(src[j]);
    ((v8s*)xpack)[t] = o;
}

// wpack layout: [mat][ks][ntile 0..15][lane][j] bf16,
//   element = W[ks*32 + (lane>>4)*8 + j][ntile*16 + (lane&15)]
__global__ __launch_bounds__(256) void pack_w(const float* __restrict__ W1,
                                              const float* __restrict__ W2,
                                              const float* __restrict__ W3,
                                              short* __restrict__ wpack) {
    const int t = blockIdx.x * 256 + threadIdx.x;
    if (t >= 3 * 8 * 16 * 64) return;
    const int lane = t & 63;
    const int nt = (t >> 6) & 15;
    const int ks = (t >> 10) & 7;
    const int mat = t >> 13;
    const float* W = (mat == 0) ? W1 : (mat == 1 ? W2 : W3);
    const int col = nt * 16 + (lane & 15);
    const int kbase = ks * 32 + ((lane >> 4) << 3);
    v8s o;
#pragma unroll
    for (int j = 0; j < 8; ++j) o[j] = (short)f2bf_rtne(W[(size_t)(kbase + j) * F + col]);
    ((v8s*)wpack)[t] = o;
}

// wave computes 16 rows x 64 cols of one output matrix; K=256 unrolled (8 MFMA k-steps)
__global__ __launch_bounds__(256) void mfma_gemm3(const short* __restrict__ xpack,
                                                  const short* __restrict__ wpack,
                                                  float* __restrict__ H1,
                                                  float* __restrict__ H2,
                                                  float* __restrict__ H3, int MT) {
    const int wid = (blockIdx.x * 256 + threadIdx.x) >> 6;
    const int lane = threadIdx.x & 63;
    const int per_mat = MT * 4;
    if (wid >= 3 * per_mat) return;
    const int mat = wid / per_mat;
    const int rem = wid - mat * per_mat;
    const int mtile = rem >> 2;
    const int ntq = rem & 3;

    const v8s* xa = (const v8s*)xpack + (size_t)mtile * (8 * 64) + lane;
    const v8s* wb = (const v8s*)wpack + (size_t)mat * (8 * 16 * 64) + ntq * (4 * 64) + lane;

    v8s a[8];
#pragma unroll
    for (int ks = 0; ks < 8; ++ks) a[ks] = xa[ks * 64];

    v4f acc[4];
#pragma unroll
    for (int nt = 0; nt < 4; ++nt) {
        v4f z = {0.f, 0.f, 0.f, 0.f};
        acc[nt] = z;
    }

#pragma unroll
    for (int ks = 0; ks < 8; ++ks) {
#pragma unroll
        for (int nt = 0; nt < 4; ++nt) {
            const v8s b = wb[ks * (16 * 64) + nt * 64];
            acc[nt] = __builtin_amdgcn_mfma_f32_16x16x32_bf16(a[ks], b, acc[nt], 0, 0, 0);
        }
    }

    float* H = (mat == 0) ? H1 : (mat == 1 ? H2 : H3);
    const int r0 = mtile * 16 + ((lane >> 4) << 2);   // C/D: row=(lane>>4)*4+reg
    const int c0 = ntq * 64 + (lane & 15);            //      col=lane&15
#pragma unroll
    for (int nt = 0; nt < 4; ++nt)
#pragma unroll
        for (int reg = 0; reg < 4; ++reg)
            H[(size_t)(r0 + reg) * F + c0 + nt * 16] = acc[nt][reg];
}

// ============ fallback vector GEMMs ============
__global__ __launch_bounds__(256) void gemm3_xw(const float* __restrict__ X,
                                                const float* __restrict__ W1,
                                                const float* __restrict__ W2,
                                                const float* __restrict__ W3,
                                                float* __restrict__ H1,
                                                float* __restrict__ H2,
                                                float* __restrict__ H3) {
    __shared__ float xs[GEMM_ROWS * F];
    const int tid = threadIdx.x;
    const int row0 = blockIdx.x * GEMM_ROWS;
#pragma unroll
    for (int r = 0; r < GEMM_ROWS; ++r)
        xs[r * F + tid] = X[(size_t)(row0 + r) * F + tid];
    __syncthreads();

    float a1[GEMM_ROWS], a2[GEMM_ROWS], a3[GEMM_ROWS];
#pragma unroll
    for (int r = 0; r < GEMM_ROWS; ++r) { a1[r] = 0.f; a2[r] = 0.f; a3[r] = 0.f; }

    const float4* xs4 = (const float4*)xs;
    for (int kk = 0; kk < F; kk += 4) {
        float w1v[4], w2v[4], w3v[4];
#pragma unroll
        for (int j = 0; j < 4; ++j) {
            w1v[j] = W1[(size_t)(kk + j) * F + tid];
            w2v[j] = W2[(size_t)(kk + j) * F + tid];
            w3v[j] = W3[(size_t)(kk + j) * F + tid];
        }
#pragma unroll
        for (int r = 0; r < GEMM_ROWS; ++r) {
            const float4 xv = xs4[r * NF4 + (kk >> 2)];
            a1[r] = fmaf(xv.x, w1v[0], a1[r]); a1[r] = fmaf(xv.y, w1v[1], a1[r]);
            a1[r] = fmaf(xv.z, w1v[2], a1[r]); a1[r] = fmaf(xv.w, w1v[3], a1[r]);
            a2[r] = fmaf(xv.x, w2v[0], a2[r]); a2[r] = fmaf(xv.y, w2v[1], a2[r]);
            a2[r] = fmaf(xv.z, w2v[2], a2[r]); a2[r] = fmaf(xv.w, w2v[3], a2[r]);
            a3[r] = fmaf(xv.x, w3v[0], a3[r]); a3[r] = fmaf(xv.y, w3v[1], a3[r]);
            a3[r] = fmaf(xv.z, w3v[2], a3[r]); a3[r] = fmaf(xv.w, w3v[3], a3[r]);
        }
    }
#pragma unroll
    for (int r = 0; r < GEMM_ROWS; ++r) {
        H1[(size_t)(row0 + r) * F + tid] = a1[r];
        H2[(size_t)(row0 + r) * F + tid] = a2[r];
        H3[(size_t)(row0 + r) * F + tid] = a3[r];
    }
}

template <bool ADD>
__global__ __launch_bounds__(256) void gemm_xw(const float* __restrict__ X,
                                               const float* __restrict__ W,
                                               const float* __restrict__ T,
                                               float* __restrict__ Out) {
    __shared__ float xs[GEMM_ROWS * F];
    const int tid = threadIdx.x;
    const int row0 = blockIdx.x * GEMM_ROWS;
#pragma unroll
    for (int r = 0; r < GEMM_ROWS; ++r)
        xs[r * F + tid] = X[(size_t)(row0 + r) * F + tid];
    __syncthreads();

    float acc[GEMM_ROWS];
#pragma unroll
    for (int r = 0; r < GEMM_ROWS; ++r)
        acc[r] = ADD ? T[(size_t)(row0 + r) * F + tid] : 0.f;

    const float4* xs4 = (const float4*)xs;
    for (int kk = 0; kk < F; kk += 4) {
        const float w0 = W[(size_t)(kk + 0) * F + tid];
        const float w1 = W[(size_t)(kk + 1) * F + tid];
        const float w2 = W[(size_t)(kk + 2) * F + tid];
        const float w3 = W[(size_t)(kk + 3) * F + tid];
#pragma unroll
        for (int r = 0; r < GEMM_ROWS; ++r) {
            const float4 xv = xs4[r * NF4 + (kk >> 2)];
            acc[r] = fmaf(xv.x, w0, acc[r]);
            acc[r] = fmaf(xv.y, w1, acc[r]);
            acc[r] = fmaf(xv.z, w2, acc[r]);
            acc[r] = fmaf(xv.w, w3, acc[r]);
        }
    }
#pragma unroll
    for (int r = 0; r < GEMM_ROWS; ++r)
        Out[(size_t)(row0 + r) * F + tid] = acc[r];
}

// ============ CSR build ============
__global__ __launch_bounds__(256) void count_kernel(const int* __restrict__ dst,
                                                    int* __restrict__ counts, int E) {
    const int e = blockIdx.x * blockDim.x + threadIdx.x;
    if (e < E) atomicAdd(&counts[dst[e]], 1);
}

__global__ __launch_bounds__(256) void scan_block(const int* __restrict__ counts,
                                                  int* __restrict__ row_start,
                                                  int* __restrict__ partials, int n) {
    __shared__ int buf[256];
    const int tid = threadIdx.x;
    const int i = blockIdx.x * 256 + tid;
    const int v = (i < n) ? counts[i] : 0;
    buf[tid] = v;
    __syncthreads();
    for (int off = 1; off < 256; off <<= 1) {
        const int t = (tid >= off) ? buf[tid - off] : 0;
        __syncthreads();
        buf[tid] += t;
        __syncthreads();
    }
    if (i < n) row_start[i] = buf[tid] - v;
    if (tid == 255) partials[blockIdx.x] = buf[255];
}

__global__ __launch_bounds__(256) void scan_partials(int* __restrict__ partials, int nb) {
    __shared__ int buf[256];
    const int tid = threadIdx.x;
    const int v = (tid < nb) ? partials[tid] : 0;
    buf[tid] = v;
    __syncthreads();
    for (int off = 1; off < 256; off <<= 1) {
        const int t = (tid >= off) ? buf[tid - off] : 0;
        __syncthreads();
        buf[tid] += t;
        __syncthreads();
    }
    if (tid < nb) partials[tid] = buf[tid] - v;
}

__global__ __launch_bounds__(256) void add_offsets(int* __restrict__ row_start,
                                                   const int* __restrict__ partials,
                                                   int* __restrict__ cursor, int n, int E) {
    const int i = blockIdx.x * blockDim.x + threadIdx.x;
    if (i < n) {
        const int v = row_start[i] + partials[i >> 8];
        row_start[i] = v;
        cursor[i] = v;
    }
    if (i == 0) row_start[n] = E;
}

__global__ __launch_bounds__(256) void scatter_kernel(const int* __restrict__ src,
                                                      const int* __restrict__ dst,
                                                      const float* __restrict__ vals,
                                                      int* __restrict__ cursor,
                                                      int2* __restrict__ pack, int E) {
    const int e = blockIdx.x * blockDim.x + threadIdx.x;
    if (e < E) {
        const int pos = atomicAdd(&cursor[dst[e]], 1);
        pack[pos] = make_int2(src[e], __float_as_int(vals[e]));
    }
}

// ============ SPMM (two waves per row; lane owns float2) ============
// addv/out2 may alias (row-local read-before-write) — deliberately NOT restrict.
__global__ __launch_bounds__(256) void spmm_csr2(const float2* __restrict__ h2,
                                                 const int* __restrict__ row_start,
                                                 const int2* __restrict__ pack,
                                                 const float2* addv,
                                                 float2* out2,
                                                 int N, int final_mode) {
    const int wid = (blockIdx.x * 256 + threadIdx.x) >> 6;
    const int lane = threadIdx.x & 63;
    const int row = wid >> 1;
    if (row >= N) return;
    const int col = ((wid & 1) << 6) + lane;   // float2 index within row: 0..127

    const int k0 = row_start[row];
    const int k1 = row_start[row + 1];

    float2 acc = addv ? addv[(size_t)row * NF2 + col] : make_float2(0.f, 0.f);

    int k = k0;
    for (; k + 4 <= k1; k += 4) {
        const int2 p0 = pack[k + 0];
        const int2 p1 = pack[k + 1];
        const int2 p2 = pack[k + 2];
        const int2 p3 = pack[k + 3];
        const float2 a0 = h2[(size_t)p0.x * NF2 + col];
        const float2 a1 = h2[(size_t)p1.x * NF2 + col];
        const float2 a2 = h2[(size_t)p2.x * NF2 + col];
        const float2 a3 = h2[(size_t)p3.x * NF2 + col];
        const float v0 = __int_as_float(p0.y), v1 = __int_as_float(p1.y);
        const float v2 = __int_as_float(p2.y), v3 = __int_as_float(p3.y);
        acc.x = fmaf(a0.x, v0, acc.x); acc.y = fmaf(a0.y, v0, acc.y);
        acc.x = fmaf(a1.x, v1, acc.x); acc.y = fmaf(a1.y, v1, acc.y);
        acc.x = fmaf(a2.x, v2, acc.x); acc.y = fmaf(a2.y, v2, acc.y);
        acc.x = fmaf(a3.x, v3, acc.x); acc.y = fmaf(a3.y, v3, acc.y);
    }
    for (; k < k1; ++k) {
        const int2 p = pack[k];
        const float v = __int_as_float(p.y);
        const float2 a = h2[(size_t)p.x * NF2 + col];
        acc.x = fmaf(a.x, v, acc.x);
        acc.y = fmaf(a.y, v, acc.y);
    }

    if (final_mode) {
        const float s = 1.0f / 3.0f;
        acc.x = fmaxf(acc.x * s, 0.f);
        acc.y = fmaxf(acc.y * s, 0.f);
    }
    out2[(size_t)row * NF2 + col] = acc;
}

// float4 one-wave-per-row variant (fallback tiers)
__global__ __launch_bounds__(256) void spmm_csr(const float4* __restrict__ h4,
                                                const int* __restrict__ row_start,
                                                const int2* __restrict__ pack,
                                                const float4* addv,
                                                float4* out4,
                                                int N, int final_mode) {
    const int gid = blockIdx.x * blockDim.x + threadIdx.x;
    const int row = gid >> 6;
    const int lane = threadIdx.x & 63;
    if (row >= N) return;

    const int k0 = row_start[row];
    const int k1 = row_start[row + 1];

    float4 acc = addv ? addv[(size_t)row * NF4 + lane]
                      : make_float4(0.f, 0.f, 0.f, 0.f);

    int k = k0;
    for (; k + 4 <= k1; k += 4) {
        const int2 p0 = pack[k + 0];
        const int2 p1 = pack[k + 1];
        const int2 p2 = pack[k + 2];
        const int2 p3 = pack[k + 3];
        const float4 h0 = h4[(size_t)p0.x * NF4 + lane];
        const float4 h1 = h4[(size_t)p1.x * NF4 + lane];
        const float4 h2 = h4[(size_t)p2.x * NF4 + lane];
        const float4 h3 = h4[(size_t)p3.x * NF4 + lane];
        const float v0 = __int_as_float(p0.y), v1 = __int_as_float(p1.y);
        const float v2 = __int_as_float(p2.y), v3 = __int_as_float(p3.y);
        acc.x = fmaf(h0.x, v0, acc.x); acc.y = fmaf(h0.y, v0, acc.y);
        acc.z = fmaf(h0.z, v0, acc.z); acc.w = fmaf(h0.w, v0, acc.w);
        acc.x = fmaf(h1.x, v1, acc.x); acc.y = fmaf(h1.y, v1, acc.y);
        acc.z = fmaf(h1.z, v1, acc.z); acc.w = fmaf(h1.w, v1, acc.w);
        acc.x = fmaf(h2.x, v2, acc.x); acc.y = fmaf(h2.y, v2, acc.y);
        acc.z = fmaf(h2.z, v2, acc.z); acc.w = fmaf(h2.w, v2, acc.w);
        acc.x = fmaf(h3.x, v3, acc.x); acc.y = fmaf(h3.y, v3, acc.y);
        acc.z = fmaf(h3.z, v3, acc.z); acc.w = fmaf(h3.w, v3, acc.w);
    }
    for (; k < k1; ++k) {
        const int2 p = pack[k];
        const float v = __int_as_float(p.y);
        const float4 hv = h4[(size_t)p.x * NF4 + lane];
        acc.x = fmaf(hv.x, v, acc.x); acc.y = fmaf(hv.y, v, acc.y);
        acc.z = fmaf(hv.z, v, acc.z); acc.w = fmaf(hv.w, v, acc.w);
    }

    if (final_mode) {
        const float s = 1.0f / 3.0f;
        acc.x = fmaxf(acc.x * s, 0.f);
        acc.y = fmaxf(acc.y * s, 0.f);
        acc.z = fmaxf(acc.z * s, 0.f);
        acc.w = fmaxf(acc.w * s, 0.f);
    }
    out4[(size_t)row * NF4 + lane] = acc;
}

extern "C" void kernel_launch(void* const* d_in, const int* in_sizes, int n_in,
                              void* d_out, int out_size, void* d_ws, size_t ws_size,
                              hipStream_t stream) {
    const float* x     = (const float*)d_in[0];
    const float* Avals = (const float*)d_in[1];
    const float* W1    = (const float*)d_in[2];
    const float* W2    = (const float*)d_in[3];
    const float* W3    = (const float*)d_in[4];
    const int*   esrc  = (const int*)d_in[5];
    const int*   edst  = (const int*)d_in[6];
    float*       out   = (float*)d_out;

    const int N = in_sizes[0] / F;   // 10000
    const int E = in_sizes[5];       // 320000

    const size_t mat_elems = (size_t)N * F;

    const int eb = (E + 255) / 256;
    const int nb = (N + 255) / 256;
    const int spmm2_grid = ((size_t)N * 128 + 255) / 256;  // 2 waves/row
    const int spmm_grid  = ((size_t)N * 64 + 255) / 256;
    const int gemm_grid  = (N + GEMM_ROWS - 1) / GEMM_ROWS;
    const int MT = N / 16;

    // tier-1 (MFMA) workspace: h2buf, h3buf, xpack, wpack, ints, pack
    const size_t need_mfma =
        2 * mat_elems * sizeof(float) + mat_elems * sizeof(short) +
        (size_t)3 * F * F * sizeof(short) +
        (size_t)(3 * N + 1 + nb + 16) * sizeof(int) + 64 + (size_t)E * 8;
    // tier-2 (fused vector) workspace
    const size_t need_fused =
        2 * mat_elems * sizeof(float) +
        (size_t)(3 * N + 1 + nb + 16) * sizeof(int) + 16 + (size_t)E * 8;

    if ((N % 16 == 0) && ws_size >= need_mfma) {
        float* h2buf     = (float*)d_ws;
        float* h3buf     = h2buf + mat_elems;
        short* xpack     = (short*)(h3buf + mat_elems);
        short* wpack     = xpack + mat_elems;
        int*   row_start = (int*)(wpack + (size_t)3 * F * F);
        int*   cursor    = row_start + (N + 1);
        int*   counts    = cursor + N;
        int*   partials  = counts + N;
        int2*  pack      = (int2*)(((uintptr_t)(partials + nb) + 7) & ~(uintptr_t)7);

        // bf16 fragment packing
        const int px_threads = MT * 8 * 64;
        pack_x<<<(px_threads + 255) / 256, 256, 0, stream>>>(x, xpack, MT);
        pack_w<<<(3 * 8 * 16 * 64 + 255) / 256, 256, 0, stream>>>(W1, W2, W3, wpack);

        // CSR build
        hipMemsetAsync(counts, 0, (size_t)N * sizeof(int), stream);
        count_kernel<<<eb, 256, 0, stream>>>(edst, counts, E);
        scan_block<<<nb, 256, 0, stream>>>(counts, row_start, partials, N);
        scan_partials<<<1, 256, 0, stream>>>(partials, nb);
        add_offsets<<<nb, 256, 0, stream>>>(row_start, partials, cursor, N, E);
        scatter_kernel<<<eb, 256, 0, stream>>>(esrc, edst, Avals, cursor, pack, E);

        // h1 -> out, h2 -> h2buf, h3 -> h3buf  (bf16 MFMA, fp32 accum)
        const int gw = 3 * MT * 4;  // total waves
        mfma_gemm3<<<(gw * 64 + 255) / 256, 256, 0, stream>>>(xpack, wpack,
                                                              out, h2buf, h3buf, MT);

        // Horner with fused adds:
        spmm_csr2<<<spmm2_grid, 256, 0, stream>>>((const float2*)h3buf, row_start, pack,
                                                  (const float2*)h2buf, (float2*)h2buf, N, 0);
        spmm_csr2<<<spmm2_grid, 256, 0, stream>>>((const float2*)h2buf, row_start, pack,
                                                  (const float2*)out, (float2*)h3buf, N, 0);
        spmm_csr2<<<spmm2_grid, 256, 0, stream>>>((const float2*)h3buf, row_start, pack,
                                                  nullptr, (float2*)out, N, 1);
    } else if (ws_size >= need_fused) {
        float* h2buf     = (float*)d_ws;
        float* h3buf     = h2buf + mat_elems;
        int*   row_start = (int*)(h3buf + mat_elems);
        int*   cursor    = row_start + (N + 1);
        int*   counts    = cursor + N;
        int*   partials  = counts + N;
        int2*  pack      = (int2*)(((uintptr_t)(partials + nb) + 7) & ~(uintptr_t)7);

        hipMemsetAsync(counts, 0, (size_t)N * sizeof(int), stream);
        count_kernel<<<eb, 256, 0, stream>>>(edst, counts, E);
        scan_block<<<nb, 256, 0, stream>>>(counts, row_start, partials, N);
        scan_partials<<<1, 256, 0, stream>>>(partials, nb);
        add_offsets<<<nb, 256, 0, stream>>>(row_start, partials, cursor, N, E);
        scatter_kernel<<<eb, 256, 0, stream>>>(esrc, edst, Avals, cursor, pack, E);

        gemm3_xw<<<gemm_grid, 256, 0, stream>>>(x, W1, W2, W3, out, h2buf, h3buf);

        spmm_csr<<<spmm_grid, 256, 0, stream>>>((const float4*)h3buf, row_start, pack,
                                                (const float4*)h2buf, (float4*)h2buf, N, 0);
        spmm_csr<<<spmm_grid, 256, 0, stream>>>((const float4*)h2buf, row_start, pack,
                                                (const float4*)out, (float4*)h3buf, N, 0);
        spmm_csr<<<spmm_grid, 256, 0, stream>>>((const float4*)h3buf, row_start, pack,
                                                nullptr, (float4*)out, N, 1);
    } else {
        // tier-3: sequential, minimal ws
        float* hbuf      = (float*)d_ws;
        int*   row_start = (int*)(hbuf + mat_elems);
        int*   cursor    = row_start + (N + 1);
        int*   counts    = cursor + N;
        int*   partials  = counts + N;
        int2*  pack      = (int2*)(((uintptr_t)(partials + nb) + 7) & ~(uintptr_t)7);

        hipMemsetAsync(counts, 0, (size_t)N * sizeof(int), stream);
        count_kernel<<<eb, 256, 0, stream>>>(edst, counts, E);
        scan_block<<<nb, 256, 0, stream>>>(counts, row_start, partials, N);
        scan_partials<<<1, 256, 0, stream>>>(partials, nb);
        add_offsets<<<nb, 256, 0, stream>>>(row_start, partials, cursor, N, E);
        scatter_kernel<<<eb, 256, 0, stream>>>(esrc, edst, Avals, cursor, pack, E);

        gemm_xw<false><<<gemm_grid, 256, 0, stream>>>(x, W3, nullptr, hbuf);
        spmm_csr<<<spmm_grid, 256, 0, stream>>>((const float4*)hbuf, row_start, pack,
                                                nullptr, (float4*)out, N, 0);
        gemm_xw<true><<<gemm_grid, 256, 0, stream>>>(x, W2, out, hbuf);
        spmm_csr<<<spmm_grid, 256, 0, stream>>>((const float4*)hbuf, row_start, pack,
                                                nullptr, (float4*)out, N, 0);
        gemm_xw<true><<<gemm_grid, 256, 0, stream>>>(x, W1, out, hbuf);
        spmm_csr<<<spmm_grid, 256, 0, stream>>>((const float4*)hbuf, row_start, pack,
                                                nullptr, (float4*)out, N, 1);
    }
}

// Round 5
// 142.869 us; speedup vs baseline: 45.5640x; 1.4075x over previous
//
#include <hip/hip_runtime.h>
#include <hip/hip_bf16.h>

#define F 256
#define NF4 (F / 4)
#define GEMM_ROWS 16
#define PW_THREADS (3 * 8 * 16 * 64)

typedef short v8s __attribute__((ext_vector_type(8)));
typedef float v4f __attribute__((ext_vector_type(4)));

__device__ __forceinline__ unsigned short f2bf_rtne(float f) {
    unsigned int u = __float_as_uint(f);
    u += 0x7FFFu + ((u >> 16) & 1u);
    return (unsigned short)(u >> 16);
}
__device__ __forceinline__ float bflo(unsigned int u) { return __uint_as_float(u << 16); }
__device__ __forceinline__ float bfhi(unsigned int u) { return __uint_as_float(u & 0xFFFF0000u); }

// ============ pack_x + pack_w + zero(counts), one dispatch ============
// xpack: [mtile][ks][lane][j] bf16 = x[mtile*16+(lane&15)][ks*32+(lane>>4)*8+j]
// wpack: [mat][ks][ntile][lane][j] bf16 = W[ks*32+(lane>>4)*8+j][ntile*16+(lane&15)]
__global__ __launch_bounds__(256) void pack_all(const float* __restrict__ X,
                                                const float* __restrict__ W1,
                                                const float* __restrict__ W2,
                                                const float* __restrict__ W3,
                                                short* __restrict__ xpack,
                                                short* __restrict__ wpack,
                                                int* __restrict__ counts,
                                                int MT, int N) {
    const int t = blockIdx.x * 256 + threadIdx.x;
    if (t < N) counts[t] = 0;

    const int PX = MT * 8 * 64;
    if (t < PX) {
        const int lane = t & 63;
        const int ks = (t >> 6) & 7;
        const int mtile = t >> 9;
        const int row = mtile * 16 + (lane & 15);
        const int kbase = ks * 32 + ((lane >> 4) << 3);
        const float* src = X + (size_t)row * F + kbase;
        v8s o;
#pragma unroll
        for (int j = 0; j < 8; ++j) o[j] = (short)f2bf_rtne(src[j]);
        ((v8s*)xpack)[t] = o;
    } else if (t < PX + PW_THREADS) {
        const int tw = t - PX;
        const int lane = tw & 63;
        const int nt = (tw >> 6) & 15;
        const int ks = (tw >> 10) & 7;
        const int mat = tw >> 13;
        const float* W = (mat == 0) ? W1 : (mat == 1 ? W2 : W3);
        const int col = nt * 16 + (lane & 15);
        const int kbase = ks * 32 + ((lane >> 4) << 3);
        v8s o;
#pragma unroll
        for (int j = 0; j < 8; ++j) o[j] = (short)f2bf_rtne(W[(size_t)(kbase + j) * F + col]);
        ((v8s*)wpack)[tw] = o;
    }
}

// ============ MFMA GEMM: H1 fp32 (=out), H2 fp32, H3 bf16 ============
__global__ __launch_bounds__(256) void mfma_gemm3(const short* __restrict__ xpack,
                                                  const short* __restrict__ wpack,
                                                  float* __restrict__ H1,
                                                  float* __restrict__ H2,
                                                  unsigned short* __restrict__ H3b,
                                                  int MT) {
    const int wid = (blockIdx.x * 256 + threadIdx.x) >> 6;
    const int lane = threadIdx.x & 63;
    const int per_mat = MT * 4;
    if (wid >= 3 * per_mat) return;
    const int mat = wid / per_mat;
    const int rem = wid - mat * per_mat;
    const int mtile = rem >> 2;
    const int ntq = rem & 3;

    const v8s* xa = (const v8s*)xpack + (size_t)mtile * (8 * 64) + lane;
    const v8s* wb = (const v8s*)wpack + (size_t)mat * (8 * 16 * 64) + ntq * (4 * 64) + lane;

    v8s a[8];
#pragma unroll
    for (int ks = 0; ks < 8; ++ks) a[ks] = xa[ks * 64];

    v4f acc[4];
#pragma unroll
    for (int nt = 0; nt < 4; ++nt) { v4f z = {0.f, 0.f, 0.f, 0.f}; acc[nt] = z; }

#pragma unroll
    for (int ks = 0; ks < 8; ++ks)
#pragma unroll
        for (int nt = 0; nt < 4; ++nt) {
            const v8s b = wb[ks * (16 * 64) + nt * 64];
            acc[nt] = __builtin_amdgcn_mfma_f32_16x16x32_bf16(a[ks], b, acc[nt], 0, 0, 0);
        }

    const int r0 = mtile * 16 + ((lane >> 4) << 2);   // C/D: row=(lane>>4)*4+reg
    const int c0 = ntq * 64 + (lane & 15);            //      col=lane&15
    if (mat == 2) {
#pragma unroll
        for (int nt = 0; nt < 4; ++nt)
#pragma unroll
            for (int reg = 0; reg < 4; ++reg)
                H3b[(size_t)(r0 + reg) * F + c0 + nt * 16] = f2bf_rtne(acc[nt][reg]);
    } else {
        float* H = (mat == 0) ? H1 : H2;
#pragma unroll
        for (int nt = 0; nt < 4; ++nt)
#pragma unroll
            for (int reg = 0; reg < 4; ++reg)
                H[(size_t)(r0 + reg) * F + c0 + nt * 16] = acc[nt][reg];
    }
}

// ============ CSR build ============
__global__ __launch_bounds__(256) void count_kernel(const int* __restrict__ dst,
                                                    int* __restrict__ counts, int E) {
    const int e = blockIdx.x * blockDim.x + threadIdx.x;
    if (e < E) atomicAdd(&counts[dst[e]], 1);
}

__global__ __launch_bounds__(256) void scan_block(const int* __restrict__ counts,
                                                  int* __restrict__ row_start,
                                                  int* __restrict__ partials, int n) {
    __shared__ int buf[256];
    const int tid = threadIdx.x;
    const int i = blockIdx.x * 256 + tid;
    const int v = (i < n) ? counts[i] : 0;
    buf[tid] = v;
    __syncthreads();
    for (int off = 1; off < 256; off <<= 1) {
        const int t = (tid >= off) ? buf[tid - off] : 0;
        __syncthreads();
        buf[tid] += t;
        __syncthreads();
    }
    if (i < n) row_start[i] = buf[tid] - v;
    if (tid == 255) partials[blockIdx.x] = buf[255];
}

// folds the partials-scan in: thread 0 of each block sums partials[0..blockIdx)
__global__ __launch_bounds__(256) void add_offsets2(int* __restrict__ row_start,
                                                    const int* __restrict__ partials,
                                                    int* __restrict__ cursor, int n, int E) {
    __shared__ int off;
    if (threadIdx.x == 0) {
        int s = 0;
        for (int j = 0; j < (int)blockIdx.x; ++j) s += partials[j];
        off = s;
    }
    __syncthreads();
    const int i = blockIdx.x * 256 + threadIdx.x;
    if (i < n) {
        const int v = row_start[i] + off;
        row_start[i] = v;
        cursor[i] = v;
    }
    if (i == 0) row_start[n] = E;
}

__global__ __launch_bounds__(256) void scatter_kernel(const int* __restrict__ src,
                                                      const int* __restrict__ dst,
                                                      const float* __restrict__ vals,
                                                      int* __restrict__ cursor,
                                                      int2* __restrict__ pack, int E) {
    const int e = blockIdx.x * blockDim.x + threadIdx.x;
    if (e < E) {
        const int pos = atomicAdd(&cursor[dst[e]], 1);
        pack[pos] = make_int2(src[e], __float_as_int(vals[e]));
    }
}

// ============ SPMM, bf16 gathers, fp32 accum ============
// one wave per row; lane owns 4 features (uint2 = 4 bf16). addv fp32 (may be h1 in d_out).
// HAS_ADD: acc init from addv. FINAL: relu(acc/3) -> float4 out; else bf16 uint2 out.
template <bool HAS_ADD, bool FINAL>
__global__ __launch_bounds__(256) void spmm_bf(const uint2* __restrict__ hb,
                                               const int* __restrict__ row_start,
                                               const int2* __restrict__ pack,
                                               const float4* __restrict__ addv,
                                               void* __restrict__ outp, int N) {
    const int wid = (blockIdx.x * 256 + threadIdx.x) >> 6;
    const int lane = threadIdx.x & 63;
    if (wid >= N) return;
    const int row = wid;

    const int k0 = row_start[row];
    const int k1 = row_start[row + 1];

    float4 acc = HAS_ADD ? addv[(size_t)row * 64 + lane]
                         : make_float4(0.f, 0.f, 0.f, 0.f);

    int k = k0;
    for (; k + 4 <= k1; k += 4) {
        const int2 p0 = pack[k + 0];
        const int2 p1 = pack[k + 1];
        const int2 p2 = pack[k + 2];
        const int2 p3 = pack[k + 3];
        const uint2 g0 = hb[(size_t)p0.x * 64 + lane];
        const uint2 g1 = hb[(size_t)p1.x * 64 + lane];
        const uint2 g2 = hb[(size_t)p2.x * 64 + lane];
        const uint2 g3 = hb[(size_t)p3.x * 64 + lane];
        const float v0 = __int_as_float(p0.y), v1 = __int_as_float(p1.y);
        const float v2 = __int_as_float(p2.y), v3 = __int_as_float(p3.y);
        acc.x = fmaf(bflo(g0.x), v0, acc.x); acc.y = fmaf(bfhi(g0.x), v0, acc.y);
        acc.z = fmaf(bflo(g0.y), v0, acc.z); acc.w = fmaf(bfhi(g0.y), v0, acc.w);
        acc.x = fmaf(bflo(g1.x), v1, acc.x); acc.y = fmaf(bfhi(g1.x), v1, acc.y);
        acc.z = fmaf(bflo(g1.y), v1, acc.z); acc.w = fmaf(bfhi(g1.y), v1, acc.w);
        acc.x = fmaf(bflo(g2.x), v2, acc.x); acc.y = fmaf(bfhi(g2.x), v2, acc.y);
        acc.z = fmaf(bflo(g2.y), v2, acc.z); acc.w = fmaf(bfhi(g2.y), v2, acc.w);
        acc.x = fmaf(bflo(g3.x), v3, acc.x); acc.y = fmaf(bfhi(g3.x), v3, acc.y);
        acc.z = fmaf(bflo(g3.y), v3, acc.z); acc.w = fmaf(bfhi(g3.y), v3, acc.w);
    }
    for (; k < k1; ++k) {
        const int2 p = pack[k];
        const uint2 g = hb[(size_t)p.x * 64 + lane];
        const float v = __int_as_float(p.y);
        acc.x = fmaf(bflo(g.x), v, acc.x); acc.y = fmaf(bfhi(g.x), v, acc.y);
        acc.z = fmaf(bflo(g.y), v, acc.z); acc.w = fmaf(bfhi(g.y), v, acc.w);
    }

    if (FINAL) {
        const float s = 1.0f / 3.0f;
        acc.x = fmaxf(acc.x * s, 0.f);
        acc.y = fmaxf(acc.y * s, 0.f);
        acc.z = fmaxf(acc.z * s, 0.f);
        acc.w = fmaxf(acc.w * s, 0.f);
        ((float4*)outp)[(size_t)row * 64 + lane] = acc;
    } else {
        uint2 o;
        o.x = (unsigned int)f2bf_rtne(acc.x) | ((unsigned int)f2bf_rtne(acc.y) << 16);
        o.y = (unsigned int)f2bf_rtne(acc.z) | ((unsigned int)f2bf_rtne(acc.w) << 16);
        ((uint2*)outp)[(size_t)row * 64 + lane] = o;
    }
}

// ============ fallback tier: fp32 vector GEMM + fp32 SPMM ============
__global__ __launch_bounds__(256) void gemm3_xw(const float* __restrict__ X,
                                                const float* __restrict__ W1,
                                                const float* __restrict__ W2,
                                                const float* __restrict__ W3,
                                                float* __restrict__ H1,
                                                float* __restrict__ H2,
                                                float* __restrict__ H3) {
    __shared__ float xs[GEMM_ROWS * F];
    const int tid = threadIdx.x;
    const int row0 = blockIdx.x * GEMM_ROWS;
#pragma unroll
    for (int r = 0; r < GEMM_ROWS; ++r)
        xs[r * F + tid] = X[(size_t)(row0 + r) * F + tid];
    __syncthreads();

    float a1[GEMM_ROWS], a2[GEMM_ROWS], a3[GEMM_ROWS];
#pragma unroll
    for (int r = 0; r < GEMM_ROWS; ++r) { a1[r] = 0.f; a2[r] = 0.f; a3[r] = 0.f; }

    const float4* xs4 = (const float4*)xs;
    for (int kk = 0; kk < F; kk += 4) {
        float w1v[4], w2v[4], w3v[4];
#pragma unroll
        for (int j = 0; j < 4; ++j) {
            w1v[j] = W1[(size_t)(kk + j) * F + tid];
            w2v[j] = W2[(size_t)(kk + j) * F + tid];
            w3v[j] = W3[(size_t)(kk + j) * F + tid];
        }
#pragma unroll
        for (int r = 0; r < GEMM_ROWS; ++r) {
            const float4 xv = xs4[r * NF4 + (kk >> 2)];
            a1[r] = fmaf(xv.x, w1v[0], a1[r]); a1[r] = fmaf(xv.y, w1v[1], a1[r]);
            a1[r] = fmaf(xv.z, w1v[2], a1[r]); a1[r] = fmaf(xv.w, w1v[3], a1[r]);
            a2[r] = fmaf(xv.x, w2v[0], a2[r]); a2[r] = fmaf(xv.y, w2v[1], a2[r]);
            a2[r] = fmaf(xv.z, w2v[2], a2[r]); a2[r] = fmaf(xv.w, w2v[3], a2[r]);
            a3[r] = fmaf(xv.x, w3v[0], a3[r]); a3[r] = fmaf(xv.y, w3v[1], a3[r]);
            a3[r] = fmaf(xv.z, w3v[2], a3[r]); a3[r] = fmaf(xv.w, w3v[3], a3[r]);
        }
    }
#pragma unroll
    for (int r = 0; r < GEMM_ROWS; ++r) {
        H1[(size_t)(row0 + r) * F + tid] = a1[r];
        H2[(size_t)(row0 + r) * F + tid] = a2[r];
        H3[(size_t)(row0 + r) * F + tid] = a3[r];
    }
}

__global__ __launch_bounds__(256) void spmm_csr(const float4* __restrict__ h4,
                                                const int* __restrict__ row_start,
                                                const int2* __restrict__ pack,
                                                const float4* addv,
                                                float4* out4,
                                                int N, int final_mode) {
    const int gid = blockIdx.x * blockDim.x + threadIdx.x;
    const int row = gid >> 6;
    const int lane = threadIdx.x & 63;
    if (row >= N) return;

    const int k0 = row_start[row];
    const int k1 = row_start[row + 1];

    float4 acc = addv ? addv[(size_t)row * NF4 + lane]
                      : make_float4(0.f, 0.f, 0.f, 0.f);

    int k = k0;
    for (; k + 4 <= k1; k += 4) {
        const int2 p0 = pack[k + 0];
        const int2 p1 = pack[k + 1];
        const int2 p2 = pack[k + 2];
        const int2 p3 = pack[k + 3];
        const float4 h0 = h4[(size_t)p0.x * NF4 + lane];
        const float4 h1 = h4[(size_t)p1.x * NF4 + lane];
        const float4 h2 = h4[(size_t)p2.x * NF4 + lane];
        const float4 h3 = h4[(size_t)p3.x * NF4 + lane];
        const float v0 = __int_as_float(p0.y), v1 = __int_as_float(p1.y);
        const float v2 = __int_as_float(p2.y), v3 = __int_as_float(p3.y);
        acc.x = fmaf(h0.x, v0, acc.x); acc.y = fmaf(h0.y, v0, acc.y);
        acc.z = fmaf(h0.z, v0, acc.z); acc.w = fmaf(h0.w, v0, acc.w);
        acc.x = fmaf(h1.x, v1, acc.x); acc.y = fmaf(h1.y, v1, acc.y);
        acc.z = fmaf(h1.z, v1, acc.z); acc.w = fmaf(h1.w, v1, acc.w);
        acc.x = fmaf(h2.x, v2, acc.x); acc.y = fmaf(h2.y, v2, acc.y);
        acc.z = fmaf(h2.z, v2, acc.z); acc.w = fmaf(h2.w, v2, acc.w);
        acc.x = fmaf(h3.x, v3, acc.x); acc.y = fmaf(h3.y, v3, acc.y);
        acc.z = fmaf(h3.z, v3, acc.z); acc.w = fmaf(h3.w, v3, acc.w);
    }
    for (; k < k1; ++k) {
        const int2 p = pack[k];
        const float v = __int_as_float(p.y);
        const float4 hv = h4[(size_t)p.x * NF4 + lane];
        acc.x = fmaf(hv.x, v, acc.x); acc.y = fmaf(hv.y, v, acc.y);
        acc.z = fmaf(hv.z, v, acc.z); acc.w = fmaf(hv.w, v, acc.w);
    }

    if (final_mode) {
        const float s = 1.0f / 3.0f;
        acc.x = fmaxf(acc.x * s, 0.f);
        acc.y = fmaxf(acc.y * s, 0.f);
        acc.z = fmaxf(acc.z * s, 0.f);
        acc.w = fmaxf(acc.w * s, 0.f);
    }
    out4[(size_t)row * NF4 + lane] = acc;
}

extern "C" void kernel_launch(void* const* d_in, const int* in_sizes, int n_in,
                              void* d_out, int out_size, void* d_ws, size_t ws_size,
                              hipStream_t stream) {
    const float* x     = (const float*)d_in[0];
    const float* Avals = (const float*)d_in[1];
    const float* W1    = (const float*)d_in[2];
    const float* W2    = (const float*)d_in[3];
    const float* W3    = (const float*)d_in[4];
    const int*   esrc  = (const int*)d_in[5];
    const int*   edst  = (const int*)d_in[6];
    float*       out   = (float*)d_out;

    const int N = in_sizes[0] / F;   // 10000
    const int E = in_sizes[5];       // 320000

    const size_t mat_elems = (size_t)N * F;
    const int eb = (E + 255) / 256;
    const int nb = (N + 255) / 256;
    const int spmm_grid = ((size_t)N * 64 + 255) / 256;
    const int gemm_grid = (N + GEMM_ROWS - 1) / GEMM_ROWS;
    const int MT = N / 16;

    // tier-1: h2f(f32) + hb0,hb1(bf16) + xpack,wpack(bf16) + ints + pack
    const size_t need_main =
        mat_elems * sizeof(float) + 2 * mat_elems * sizeof(short) +
        mat_elems * sizeof(short) + (size_t)3 * F * F * sizeof(short) +
        (size_t)(3 * N + 1 + nb + 16) * sizeof(int) + 64 + (size_t)E * 8;
    const size_t need_fused =
        2 * mat_elems * sizeof(float) +
        (size_t)(3 * N + 1 + nb + 16) * sizeof(int) + 16 + (size_t)E * 8;

    if ((N % 16 == 0) && ws_size >= need_main) {
        float*          h2f   = (float*)d_ws;
        unsigned short* hb0   = (unsigned short*)(h2f + mat_elems);   // h3 / t2
        unsigned short* hb1   = hb0 + mat_elems;                      // t1
        short*          xpack = (short*)(hb1 + mat_elems);
        short*          wpack = xpack + mat_elems;
        int*   row_start = (int*)(wpack + (size_t)3 * F * F);
        int*   cursor    = row_start + (N + 1);
        int*   counts    = cursor + N;
        int*   partials  = counts + N;
        int2*  pack      = (int2*)(((uintptr_t)(partials + nb) + 7) & ~(uintptr_t)7);

        const int PX = MT * 8 * 64;
        pack_all<<<(PX + PW_THREADS + 255) / 256, 256, 0, stream>>>(
            x, W1, W2, W3, xpack, wpack, counts, MT, N);

        count_kernel<<<eb, 256, 0, stream>>>(edst, counts, E);
        scan_block<<<nb, 256, 0, stream>>>(counts, row_start, partials, N);
        add_offsets2<<<nb, 256, 0, stream>>>(row_start, partials, cursor, N, E);
        scatter_kernel<<<eb, 256, 0, stream>>>(esrc, edst, Avals, cursor, pack, E);

        // h1 -> out (f32), h2 -> h2f (f32), h3 -> hb0 (bf16)
        const int gw = 3 * MT * 4;
        mfma_gemm3<<<(gw * 64 + 255) / 256, 256, 0, stream>>>(xpack, wpack,
                                                              out, h2f, hb0, MT);

        // t1 = A h3 + h2 -> hb1 (bf16)
        spmm_bf<true, false><<<spmm_grid, 256, 0, stream>>>(
            (const uint2*)hb0, row_start, pack, (const float4*)h2f, hb1, N);
        // t2 = A t1 + h1 -> hb0 (bf16)
        spmm_bf<true, false><<<spmm_grid, 256, 0, stream>>>(
            (const uint2*)hb1, row_start, pack, (const float4*)out, hb0, N);
        // out = relu(A t2 / 3) -> fp32
        spmm_bf<false, true><<<spmm_grid, 256, 0, stream>>>(
            (const uint2*)hb0, row_start, pack, nullptr, out, N);
    } else if (ws_size >= need_fused) {
        float* h2buf     = (float*)d_ws;
        float* h3buf     = h2buf + mat_elems;
        int*   row_start = (int*)(h3buf + mat_elems);
        int*   cursor    = row_start + (N + 1);
        int*   counts    = cursor + N;
        int*   partials  = counts + N;
        int2*  pack      = (int2*)(((uintptr_t)(partials + nb) + 7) & ~(uintptr_t)7);

        hipMemsetAsync(counts, 0, (size_t)N * sizeof(int), stream);
        count_kernel<<<eb, 256, 0, stream>>>(edst, counts, E);
        scan_block<<<nb, 256, 0, stream>>>(counts, row_start, partials, N);
        add_offsets2<<<nb, 256, 0, stream>>>(row_start, partials, cursor, N, E);
        scatter_kernel<<<eb, 256, 0, stream>>>(esrc, edst, Avals, cursor, pack, E);

        gemm3_xw<<<gemm_grid, 256, 0, stream>>>(x, W1, W2, W3, out, h2buf, h3buf);

        spmm_csr<<<spmm_grid, 256, 0, stream>>>((const float4*)h3buf, row_start, pack,
                                                (const float4*)h2buf, (float4*)h2buf, N, 0);
        spmm_csr<<<spmm_grid, 256, 0, stream>>>((const float4*)h2buf, row_start, pack,
                                                (const float4*)out, (float4*)h3buf, N, 0);
        spmm_csr<<<spmm_grid, 256, 0, stream>>>((const float4*)h3buf, row_start, pack,
                                                nullptr, (float4*)out, N, 1);
    }
}